// Round 19
// baseline (297.387 us; speedup 1.0000x reference)
//
#include <hip/hip_runtime.h>

#define NDIMC 2
#define NCELLS 1000
#define BATCHSZ 4
#define NSTEPS 251
#define XROW 2007   // 2 + NCELLS*NDIM + 5

typedef float v2f __attribute__((ext_vector_type(2)));
typedef float v4f __attribute__((ext_vector_type(4)));

__device__ __forceinline__ v2f vlo(v4f v) { return __builtin_shufflevector(v, v, 0, 1); }
__device__ __forceinline__ v2f vhi(v4f v) { return __builtin_shufflevector(v, v, 2, 3); }

// Packed fp32 fma without inline asm: backend selects v_pk_fma_f32 (R6-verified).
__device__ __forceinline__ v2f pfma(v2f w, v2f v, v2f a) {
    return __builtin_elementwise_fma(w, v, a);
}

__device__ __forceinline__ float fast_tanh(float x) {
    // tanh(x) = 1 - 2/(exp(2x)+1); exp2 form, exact +-1 saturation
    float e = __builtin_amdgcn_exp2f(x * 2.885390081777926774f);
    float r = __builtin_amdgcn_rcpf(e + 1.0f);
    return fmaf(-2.0f, r, 1.0f);
}

// R8-verified: NO explicit LDS fences needed (same-wave DS ops are in-order;
// counted lgkmcnt covers read->use).

// DPP lane permute / add (VALU pipe, row-local, ~4-8cy).
template<int CTRL>
__device__ __forceinline__ float dpp_mov(float x) {
    return __int_as_float(__builtin_amdgcn_update_dpp(
        0, __float_as_int(x), CTRL, 0xf, 0xf, true));
}
template<int CTRL>
__device__ __forceinline__ float dpp_add(float z) { return z + dpp_mov<CTRL>(z); }

// Sum across each 16-lane row (xor masks 1,3,7,15 - independent).
__device__ __forceinline__ float row16_sum(float z) {
    z = dpp_add<0xB1>(z);    // xor1  (quad_perm 1,0,3,2)
    z = dpp_add<0x1B>(z);    // xor3  (quad_perm 3,2,1,0)
    z = dpp_add<0x141>(z);   // xor7  (row_half_mirror)
    z = dpp_add<0x140>(z);   // xor15 (row_mirror)
    return z;
}

// Fetch partner row's (lane^16) value via v_permlane16_swap_b32
// (R4/R10/R16-verified): odd rows take t, even take u.
__device__ __forceinline__ float xor16(float z, bool odd) {
    float t = z, u = z;
    asm("v_permlane16_swap_b32 %0, %1" : "+v"(t), "+v"(u));
    return odd ? t : u;
}

// Row-local all-gather of 16 values into 8 v2f pairs via DPP butterfly.
// Pair t component c holds the value from row-lane (s16 ^ TAU[t] ^ c),
// TAU = {0,2,7,5,15,13,8,10}  (R4/R7/R13-verified end-to-end, absmax 0.0).
struct G16 { v2f p[8]; };
__device__ __forceinline__ G16 gather16(float z) {
    G16 g;
    const float v0 = z;
    const float v1 = dpp_mov<0x4E>(v0);    // xor2 (quad_perm 2,3,0,1)
    const float v2 = dpp_mov<0x141>(v0);   // xor7
    const float v3 = dpp_mov<0x141>(v1);   // xor5
    const float v4 = dpp_mov<0x140>(v0);   // xor15
    const float v5 = dpp_mov<0x140>(v1);   // xor13
    const float v6 = dpp_mov<0x140>(v2);   // xor8
    const float v7 = dpp_mov<0x140>(v3);   // xor10
    g.p[0] = v2f{v0, dpp_mov<0xB1>(v0)};
    g.p[1] = v2f{v1, dpp_mov<0xB1>(v1)};
    g.p[2] = v2f{v2, dpp_mov<0xB1>(v2)};
    g.p[3] = v2f{v3, dpp_mov<0xB1>(v3)};
    g.p[4] = v2f{v4, dpp_mov<0xB1>(v4)};
    g.p[5] = v2f{v5, dpp_mov<0xB1>(v5)};
    g.p[6] = v2f{v6, dpp_mov<0xB1>(v6)};
    g.p[7] = v2f{v7, dpp_mov<0xB1>(v7)};
    return g;
}

// 16-input dot against TAU-permuted packed weights (R7/R13-verified).
__device__ __forceinline__ float gdot16(const v2f (&w)[8], const G16& g, float bias) {
    v2f a0 = {bias, 0.f}, a1 = {0.f, 0.f}, a2 = {0.f, 0.f}, a3 = {0.f, 0.f};
    a0 = pfma(w[0], g.p[0], a0); a1 = pfma(w[1], g.p[1], a1);
    a2 = pfma(w[2], g.p[2], a2); a3 = pfma(w[3], g.p[3], a3);
    a0 = pfma(w[4], g.p[4], a0); a1 = pfma(w[5], g.p[5], a1);
    a2 = pfma(w[6], g.p[6], a2); a3 = pfma(w[7], g.p[7], a3);
    v2f s = (a0 + a1) + (a2 + a3);
    return s[0] + s[1];
}

// 32-float dot (16 packed pairs) from LDS — R6-identical tree.
__device__ __forceinline__ float pdot32(const v2f (&w)[16], const float* p, float bias) {
    v2f a0 = {bias, 0.f}, a1 = {0.f, 0.f}, a2 = {0.f, 0.f}, a3 = {0.f, 0.f};
    #pragma unroll
    for (int c = 0; c < 2; ++c) {
        v4f u0 = *(const v4f*)(p + c * 16);
        v4f u1 = *(const v4f*)(p + c * 16 + 4);
        v4f u2 = *(const v4f*)(p + c * 16 + 8);
        v4f u3 = *(const v4f*)(p + c * 16 + 12);
        a0 = pfma(w[c*8+0], vlo(u0), a0); a1 = pfma(w[c*8+1], vhi(u0), a1);
        a2 = pfma(w[c*8+2], vlo(u1), a2); a3 = pfma(w[c*8+3], vhi(u1), a3);
        a0 = pfma(w[c*8+4], vlo(u2), a0); a1 = pfma(w[c*8+5], vhi(u2), a1);
        a2 = pfma(w[c*8+6], vlo(u3), a2); a3 = pfma(w[c*8+7], vhi(u3), a3);
    }
    v2f s = (a0 + a1) + (a2 + a3);
    return s[0] + s[1];
}

__global__ __launch_bounds__(64, 2)
void phinn_sde_kernel(const float* __restrict__ x,   const float* __restrict__ dw,
                      const float* __restrict__ pw1, const float* __restrict__ pb1,
                      const float* __restrict__ pw2, const float* __restrict__ pb2,
                      const float* __restrict__ pw3, const float* __restrict__ pb3,
                      const float* __restrict__ pw4, const float* __restrict__ pb4,
                      const float* __restrict__ pw5, const float* __restrict__ pb5,
                      const float* __restrict__ tw,  const float* __restrict__ tb,
                      float* __restrict__ out)
{
    // R17 + g3 via DPP gather (R13-verified). LDS only for the two genuinely
    // cross-row stages: 0:h2(32) 1:g3(32).
    __shared__ __align__(16) float sh[2][2][32];

    const int tid  = threadIdx.x;
    const int n    = tid & 31;          // neuron id within the 32-group
    const int grp  = tid >> 5;          // which of the wave's two cells
    const int s16  = n & 15;
    const int hi   = n >> 4;            // k-half for split stages
    const bool odd = hi;                // row parity within the 32-group
    const int b    = blockIdx.x / (NCELLS / 2);
    const int pair = blockIdx.x % (NCELLS / 2);
    const int cell = pair * 2 + grp;

    const int TAU[8] = {0, 2, 7, 5, 15, 13, 8, 10};

    // ---- per-lane register-resident weights (loaded once, used 251x) ----
    const float r1a = pw1[s16 * 2 + 0];
    const float r1b = pw1[s16 * 2 + 1];
    const float rb1 = pb1[s16];
    const float rb2 = pb2[n];
    const float rb3 = pb3[n];
    const float rb4 = pb4[s16];

    v2f w2f[8], w4f[8], w2cp[8], w4cp[8];   // TAU-permuted (gather consumers)
    #pragma unroll
    for (int t = 0; t < 8; ++t) {
        const int j0 = s16 ^ TAU[t];
        const int j1 = j0 ^ 1;
        const int k0 = hi * 16 + j0;     // own k-half (32-wide inputs)
        const int k1 = hi * 16 + j1;
        w2f[t]  = v2f{pw2[n * 16 + j0],   pw2[n * 16 + j1]};    // h2 (R7)
        w4f[t]  = v2f{pw4[s16 * 32 + k0], pw4[s16 * 32 + k1]};  // h4 split (R7)
        w2cp[t] = v2f{pw2[k0 * 16 + s16], pw2[k1 * 16 + s16]};  // g1 split (R7)
        w4cp[t] = v2f{pw4[j0 * 32 + n] * pw5[j0],               // g3, rw5-folded (R13)
                      pw4[j1 * 32 + n] * pw5[j1]};
    }

    v2f w3p[16];                         // pw3 row n (32 in)  - h3 (LDS)
    #pragma unroll
    for (int j = 0; j < 16; ++j) w3p[j] = ((const v2f*)pw3)[n * 16 + j];

    v2f w3cp[16];                        // pw3 column n (32 rows) - g2 (LDS)
    #pragma unroll
    for (int j = 0; j < 16; ++j)
        w3cp[j] = v2f{pw3[(2*j) * 32 + n], pw3[(2*j+1) * 32 + n]};

    // ---- per-batch scalars & both tilt candidates ----
    const float* xb = x + (size_t)b * XROW;
    const float t0v    = xb[0];
    const float tcritv = xb[2 + NCELLS * NDIMC];       // index 2002
    const float p0x = xb[2003], p0y = xb[2004];
    const float p1x = xb[2005], p1y = xb[2006];
    const float tA0 = fmaf(p0x, tw[0], fmaf(p0y, tw[1], tb[0]));
    const float tA1 = fmaf(p0x, tw[2], fmaf(p0y, tw[3], tb[1]));
    const float tB0 = fmaf(p1x, tw[0], fmaf(p1y, tw[1], tb[0]));
    const float tB1 = fmaf(p1x, tw[2], fmaf(p1y, tw[3], tb[1]));

    float y0 = xb[2 + cell * 2 + 0];
    float y1 = xb[2 + cell * 2 + 1];

    // dw addressing: wave-uniform SGPR base + per-lane 32-bit element offset
    const float* dwb = dw + (size_t)b * NSTEPS * NCELLS * NDIMC
                          + (size_t)pair * 2 * NDIMC;
    int dwoff = grp * NDIMC;

    const float* l0 = &sh[grp][0][0];    // h2
    const float* l1 = &sh[grp][1][0];    // g3

    #pragma unroll 1
    for (int i = 0; i < NSTEPS; ++i) {
        // prefetch this step's noise early; consumed at the very end
        const float2 dwv = *(const float2*)(dwb + dwoff);
        dwoff += NCELLS * NDIMC;
        const float t = t0v + 0.001f * (float)i;

        // ---------- forward ----------
        const float h1 = fast_tanh(fmaf(r1a, y0, fmaf(r1b, y1, rb1)));

        // h2: 16-in via DPP gather (row-local; h1 dup across rows)
        const G16 G1 = gather16(h1);
        const float h2 = fast_tanh(gdot16(w2f, G1, rb2));
        sh[grp][0][n] = h2;

        // h3: 32-in, cross-row -> LDS
        const float h3 = fast_tanh(pdot32(w3p, l0, rb3));

        // h4: 32-in split-K; row hi holds exactly k in [16hi,16hi+16) -> gather
        const G16 G3 = gather16(h3);
        const float A4 = gdot16(w4f, G3, 0.f);
        const float h4 = fast_tanh(A4 + xor16(A4, odd) + rb4);

        // ---------- backward (grad of sum(phi) wrt y) ----------
        const float d4 = fmaf(-h4, h4, 1.0f);      // rw5 folded into w4cp

        // g3: 16-in via DPP gather (d4 dup across rows; R13-verified)
        const G16 G4 = gather16(d4);
        const float g3p = gdot16(w4cp, G4, 0.f) * fmaf(-h3, h3, 1.0f);
        sh[grp][1][n] = g3p;

        // g2: 32-in, cross-row -> LDS
        const float g2p = pdot32(w3cp, l1, 0.f) * fmaf(-h2, h2, 1.0f);

        // g1: 32-in split-K; row-local values -> gather
        const G16 G6 = gather16(g2p);
        const float A1 = gdot16(w2cp, G6, 0.f);
        const float g1p = (A1 + xor16(A1, odd)) * fmaf(-h1, h1, 1.0f);

        // gy[d] = sum_{j<16} pw1[j][d] * g1p[j] (g1p full in all lanes)
        const float v0 = row16_sum(r1a * g1p);
        const float v1 = row16_sum(r1b * g1p);

        // ---------- update (identical in all lanes of the group) ----------
        const bool  cnd   = t < tcritv;
        const float tilt0 = cnd ? tA0 : tB0;
        const float tilt1 = cnd ? tA1 : tB1;
        y0 = fmaf(-0.001f, v0 + tilt0, fmaf(0.001f, dwv.x, y0));
        y1 = fmaf(-0.001f, v1 + tilt1, fmaf(0.001f, dwv.y, y1));
    }

    if (n == 0) {
        *(float2*)(out + ((size_t)b * NCELLS + cell) * NDIMC) = make_float2(y0, y1);
    }
}

extern "C" void kernel_launch(void* const* d_in, const int* in_sizes, int n_in,
                              void* d_out, int out_size, void* d_ws, size_t ws_size,
                              hipStream_t stream) {
    const float* x   = (const float*)d_in[0];
    const float* dw  = (const float*)d_in[1];
    const float* pw1 = (const float*)d_in[2];
    const float* pb1 = (const float*)d_in[3];
    const float* pw2 = (const float*)d_in[4];
    const float* pb2 = (const float*)d_in[5];
    const float* pw3 = (const float*)d_in[6];
    const float* pb3 = (const float*)d_in[7];
    const float* pw4 = (const float*)d_in[8];
    const float* pb4 = (const float*)d_in[9];
    const float* pw5 = (const float*)d_in[10];
    const float* pb5 = (const float*)d_in[11];
    const float* tw  = (const float*)d_in[12];
    const float* tb  = (const float*)d_in[13];
    float* out = (float*)d_out;

    dim3 grid(BATCHSZ * NCELLS / 2);   // 2000 single-wave blocks (2 cells each)
    dim3 block(64);
    phinn_sde_kernel<<<grid, block, 0, stream>>>(x, dw, pw1, pb1, pw2, pb2,
                                                 pw3, pb3, pw4, pb4, pw5, pb5,
                                                 tw, tb, out);
}

// Round 20
// 252.235 us; speedup vs baseline: 1.1790x; 1.1790x over previous
//
#include <hip/hip_runtime.h>

#define NDIMC 2
#define NCELLS 1000
#define BATCHSZ 4
#define NSTEPS 251
#define XROW 2007   // 2 + NCELLS*NDIM + 5

typedef float v2f __attribute__((ext_vector_type(2)));
typedef float v4f __attribute__((ext_vector_type(4)));

__device__ __forceinline__ v2f vlo(v4f v) { return __builtin_shufflevector(v, v, 0, 1); }
__device__ __forceinline__ v2f vhi(v4f v) { return __builtin_shufflevector(v, v, 2, 3); }

// Packed fp32 fma without inline asm: backend selects v_pk_fma_f32 (R6-verified).
__device__ __forceinline__ v2f pfma(v2f w, v2f v, v2f a) {
    return __builtin_elementwise_fma(w, v, a);
}

__device__ __forceinline__ float fast_tanh(float x) {
    // tanh(x) = 1 - 2/(exp(2x)+1); exp2 form, exact +-1 saturation
    float e = __builtin_amdgcn_exp2f(x * 2.885390081777926774f);
    float r = __builtin_amdgcn_rcpf(e + 1.0f);
    return fmaf(-2.0f, r, 1.0f);
}

// R8-verified: NO explicit LDS fences needed (same-wave DS ops are in-order;
// counted lgkmcnt covers read->use).

// DPP lane permute / add (VALU pipe, row-local, ~4-8cy).
template<int CTRL>
__device__ __forceinline__ float dpp_mov(float x) {
    return __int_as_float(__builtin_amdgcn_update_dpp(
        0, __float_as_int(x), CTRL, 0xf, 0xf, true));
}
template<int CTRL>
__device__ __forceinline__ float dpp_add(float z) { return z + dpp_mov<CTRL>(z); }

// Sum across each 16-lane row (xor masks 1,3,7,15 - independent).
__device__ __forceinline__ float row16_sum(float z) {
    z = dpp_add<0xB1>(z);    // xor1  (quad_perm 1,0,3,2)
    z = dpp_add<0x1B>(z);    // xor3  (quad_perm 3,2,1,0)
    z = dpp_add<0x141>(z);   // xor7  (row_half_mirror)
    z = dpp_add<0x140>(z);   // xor15 (row_mirror)
    return z;
}

// Fetch partner row's (lane^16) value via v_permlane16_swap_b32
// (R4/R10/R16-verified): odd rows take t, even take u.
__device__ __forceinline__ float xor16(float z, bool odd) {
    float t = z, u = z;
    asm("v_permlane16_swap_b32 %0, %1" : "+v"(t), "+v"(u));
    return odd ? t : u;
}

// Row-local all-gather of 16 values into 8 v2f pairs via DPP butterfly.
// Pair t component c holds the value from row-lane (s16 ^ TAU[t] ^ c),
// TAU = {0,2,7,5,15,13,8,10}  (R4/R7-verified end-to-end, absmax 0.0).
struct G16 { v2f p[8]; };
__device__ __forceinline__ G16 gather16(float z) {
    G16 g;
    const float v0 = z;
    const float v1 = dpp_mov<0x4E>(v0);    // xor2 (quad_perm 2,3,0,1)
    const float v2 = dpp_mov<0x141>(v0);   // xor7
    const float v3 = dpp_mov<0x141>(v1);   // xor5
    const float v4 = dpp_mov<0x140>(v0);   // xor15
    const float v5 = dpp_mov<0x140>(v1);   // xor13
    const float v6 = dpp_mov<0x140>(v2);   // xor8
    const float v7 = dpp_mov<0x140>(v3);   // xor10
    g.p[0] = v2f{v0, dpp_mov<0xB1>(v0)};
    g.p[1] = v2f{v1, dpp_mov<0xB1>(v1)};
    g.p[2] = v2f{v2, dpp_mov<0xB1>(v2)};
    g.p[3] = v2f{v3, dpp_mov<0xB1>(v3)};
    g.p[4] = v2f{v4, dpp_mov<0xB1>(v4)};
    g.p[5] = v2f{v5, dpp_mov<0xB1>(v5)};
    g.p[6] = v2f{v6, dpp_mov<0xB1>(v6)};
    g.p[7] = v2f{v7, dpp_mov<0xB1>(v7)};
    return g;
}

// 16-input dot against TAU-permuted packed weights (R7-verified).
__device__ __forceinline__ float gdot16(const v2f (&w)[8], const G16& g, float bias) {
    v2f a0 = {bias, 0.f}, a1 = {0.f, 0.f}, a2 = {0.f, 0.f}, a3 = {0.f, 0.f};
    a0 = pfma(w[0], g.p[0], a0); a1 = pfma(w[1], g.p[1], a1);
    a2 = pfma(w[2], g.p[2], a2); a3 = pfma(w[3], g.p[3], a3);
    a0 = pfma(w[4], g.p[4], a0); a1 = pfma(w[5], g.p[5], a1);
    a2 = pfma(w[6], g.p[6], a2); a3 = pfma(w[7], g.p[7], a3);
    v2f s = (a0 + a1) + (a2 + a3);
    return s[0] + s[1];
}

// 8-float partial dot (split half of a 16-in layer) from LDS — R10/R16 tree.
__device__ __forceinline__ float pdot8h(const v2f (&w)[4], const float* p) {
    v4f u0 = *(const v4f*)(p);
    v4f u1 = *(const v4f*)(p + 4);
    v2f a0 = {0.f, 0.f}, a1 = {0.f, 0.f};
    a0 = pfma(w[0], vlo(u0), a0); a1 = pfma(w[1], vhi(u0), a1);
    a0 = pfma(w[2], vlo(u1), a0); a1 = pfma(w[3], vhi(u1), a1);
    v2f s = a0 + a1;
    return s[0] + s[1];
}

// 32-float dot (16 packed pairs) from LDS — R6-identical tree.
__device__ __forceinline__ float pdot32(const v2f (&w)[16], const float* p, float bias) {
    v2f a0 = {bias, 0.f}, a1 = {0.f, 0.f}, a2 = {0.f, 0.f}, a3 = {0.f, 0.f};
    #pragma unroll
    for (int c = 0; c < 2; ++c) {
        v4f u0 = *(const v4f*)(p + c * 16);
        v4f u1 = *(const v4f*)(p + c * 16 + 4);
        v4f u2 = *(const v4f*)(p + c * 16 + 8);
        v4f u3 = *(const v4f*)(p + c * 16 + 12);
        a0 = pfma(w[c*8+0], vlo(u0), a0); a1 = pfma(w[c*8+1], vhi(u0), a1);
        a2 = pfma(w[c*8+2], vlo(u1), a2); a3 = pfma(w[c*8+3], vhi(u1), a3);
        a0 = pfma(w[c*8+4], vlo(u2), a0); a1 = pfma(w[c*8+5], vhi(u2), a1);
        a2 = pfma(w[c*8+6], vlo(u3), a2); a3 = pfma(w[c*8+7], vhi(u3), a3);
    }
    v2f s = (a0 + a1) + (a2 + a3);
    return s[0] + s[1];
}

__global__ __launch_bounds__(64, 2)
void phinn_sde_kernel(const float* __restrict__ x,   const float* __restrict__ dw,
                      const float* __restrict__ pw1, const float* __restrict__ pb1,
                      const float* __restrict__ pw2, const float* __restrict__ pb2,
                      const float* __restrict__ pw3, const float* __restrict__ pb3,
                      const float* __restrict__ pw4, const float* __restrict__ pb4,
                      const float* __restrict__ pw5, const float* __restrict__ pb5,
                      const float* __restrict__ tw,  const float* __restrict__ tb,
                      float* __restrict__ out)
{
    // Champion (R17): R16 split-K skeleton + DPP gather on the three
    // ROW-LOCAL stages (h1->h2, h3->h4 split, g2->g1 split). LDS for the
    // latency-hidden stages: 0:h2(32) 1:d4(16) 2:g3(32).
    __shared__ __align__(16) float sh[2][3][32];

    const int tid  = threadIdx.x;
    const int n    = tid & 31;          // neuron id within the 32-group
    const int grp  = tid >> 5;          // which of the wave's two cells
    const int s16  = n & 15;
    const int hi   = n >> 4;            // k-half for split stages
    const bool odd = hi;                // row parity within the 32-group
    const int b    = blockIdx.x / (NCELLS / 2);
    const int pair = blockIdx.x % (NCELLS / 2);
    const int cell = pair * 2 + grp;

    const int TAU[8] = {0, 2, 7, 5, 15, 13, 8, 10};

    // ---- per-lane register-resident weights (loaded once, used 251x) ----
    const float r1a = pw1[s16 * 2 + 0];
    const float r1b = pw1[s16 * 2 + 1];
    const float rb1 = pb1[s16];
    const float rb2 = pb2[n];
    const float rb3 = pb3[n];
    const float rb4 = pb4[s16];

    v2f w2f[8], w4f[8], w2cp[8];         // TAU-permuted (gather consumers)
    #pragma unroll
    for (int t = 0; t < 8; ++t) {
        const int j0 = s16 ^ TAU[t];
        const int j1 = j0 ^ 1;
        const int k0 = hi * 16 + j0;     // own k-half (32-wide inputs)
        const int k1 = hi * 16 + j1;
        w2f[t]  = v2f{pw2[n * 16 + j0],   pw2[n * 16 + j1]};    // h2 (R7-verified)
        w4f[t]  = v2f{pw4[s16 * 32 + k0], pw4[s16 * 32 + k1]};  // h4 split (R7)
        w2cp[t] = v2f{pw2[k0 * 16 + s16], pw2[k1 * 16 + s16]};  // g1 split (R7)
    }

    v2f w3p[16];                         // pw3 row n (32 in)  - h3 (LDS)
    #pragma unroll
    for (int j = 0; j < 16; ++j) w3p[j] = ((const v2f*)pw3)[n * 16 + j];

    v2f w4cp[4];                         // pw4 col n rows hi*8.., rw5-folded - g3 (LDS split, R16)
    #pragma unroll
    for (int j = 0; j < 4; ++j)
        w4cp[j] = v2f{pw4[(hi*8 + 2*j)     * 32 + n] * pw5[hi*8 + 2*j],
                      pw4[(hi*8 + 2*j + 1) * 32 + n] * pw5[hi*8 + 2*j + 1]};

    v2f w3cp[16];                        // pw3 column n (32 rows) - g2 (LDS)
    #pragma unroll
    for (int j = 0; j < 16; ++j)
        w3cp[j] = v2f{pw3[(2*j) * 32 + n], pw3[(2*j+1) * 32 + n]};

    // ---- per-batch scalars & both tilt candidates ----
    const float* xb = x + (size_t)b * XROW;
    const float t0v    = xb[0];
    const float tcritv = xb[2 + NCELLS * NDIMC];       // index 2002
    const float p0x = xb[2003], p0y = xb[2004];
    const float p1x = xb[2005], p1y = xb[2006];
    const float tA0 = fmaf(p0x, tw[0], fmaf(p0y, tw[1], tb[0]));
    const float tA1 = fmaf(p0x, tw[2], fmaf(p0y, tw[3], tb[1]));
    const float tB0 = fmaf(p1x, tw[0], fmaf(p1y, tw[1], tb[0]));
    const float tB1 = fmaf(p1x, tw[2], fmaf(p1y, tw[3], tb[1]));

    float y0 = xb[2 + cell * 2 + 0];
    float y1 = xb[2 + cell * 2 + 1];

    // dw addressing: wave-uniform SGPR base + per-lane 32-bit element offset
    const float* dwb = dw + (size_t)b * NSTEPS * NCELLS * NDIMC
                          + (size_t)pair * 2 * NDIMC;
    int dwoff = grp * NDIMC;

    const float* l0 = &sh[grp][0][0];    // h2
    const float* l1 = &sh[grp][1][0];    // d4
    const float* l2 = &sh[grp][2][0];    // g3

    #pragma unroll 1
    for (int i = 0; i < NSTEPS; ++i) {
        // prefetch this step's noise early; consumed at the very end
        const float2 dwv = *(const float2*)(dwb + dwoff);
        dwoff += NCELLS * NDIMC;
        const float t = t0v + 0.001f * (float)i;

        // ---------- forward ----------
        const float h1 = fast_tanh(fmaf(r1a, y0, fmaf(r1b, y1, rb1)));

        // h2: 16-in via DPP gather (row-local; h1 dup across rows)
        const G16 G1 = gather16(h1);
        const float h2 = fast_tanh(gdot16(w2f, G1, rb2));
        sh[grp][0][n] = h2;

        // h3: 32-in, cross-row -> LDS
        const float h3 = fast_tanh(pdot32(w3p, l0, rb3));

        // h4: 32-in split-K; row hi holds exactly k in [16hi,16hi+16) -> gather
        const G16 G3 = gather16(h3);
        const float A4 = gdot16(w4f, G3, 0.f);
        const float h4 = fast_tanh(A4 + xor16(A4, odd) + rb4);

        // ---------- backward (grad of sum(phi) wrt y) ----------
        const float d4 = fmaf(-h4, h4, 1.0f);      // rw5 folded into w4cp
        sh[grp][1][n] = d4;

        // g3: 16-in split across halves (LDS; d4 dup across rows)
        const float q3 = pdot8h(w4cp, l1 + hi * 8);
        const float g3p = (q3 + xor16(q3, odd)) * fmaf(-h3, h3, 1.0f);
        sh[grp][2][n] = g3p;

        // g2: 32-in, cross-row -> LDS
        const float g2p = pdot32(w3cp, l2, 0.f) * fmaf(-h2, h2, 1.0f);

        // g1: 32-in split-K; row-local values -> gather
        const G16 G6 = gather16(g2p);
        const float A1 = gdot16(w2cp, G6, 0.f);
        const float g1p = (A1 + xor16(A1, odd)) * fmaf(-h1, h1, 1.0f);

        // gy[d] = sum_{j<16} pw1[j][d] * g1p[j] (g1p full in all lanes)
        const float v0 = row16_sum(r1a * g1p);
        const float v1 = row16_sum(r1b * g1p);

        // ---------- update (identical in all lanes of the group) ----------
        const bool  cnd   = t < tcritv;
        const float tilt0 = cnd ? tA0 : tB0;
        const float tilt1 = cnd ? tA1 : tB1;
        y0 = fmaf(-0.001f, v0 + tilt0, fmaf(0.001f, dwv.x, y0));
        y1 = fmaf(-0.001f, v1 + tilt1, fmaf(0.001f, dwv.y, y1));
    }

    if (n == 0) {
        *(float2*)(out + ((size_t)b * NCELLS + cell) * NDIMC) = make_float2(y0, y1);
    }
}

extern "C" void kernel_launch(void* const* d_in, const int* in_sizes, int n_in,
                              void* d_out, int out_size, void* d_ws, size_t ws_size,
                              hipStream_t stream) {
    const float* x   = (const float*)d_in[0];
    const float* dw  = (const float*)d_in[1];
    const float* pw1 = (const float*)d_in[2];
    const float* pb1 = (const float*)d_in[3];
    const float* pw2 = (const float*)d_in[4];
    const float* pb2 = (const float*)d_in[5];
    const float* pw3 = (const float*)d_in[6];
    const float* pb3 = (const float*)d_in[7];
    const float* pw4 = (const float*)d_in[8];
    const float* pb4 = (const float*)d_in[9];
    const float* pw5 = (const float*)d_in[10];
    const float* pb5 = (const float*)d_in[11];
    const float* tw  = (const float*)d_in[12];
    const float* tb  = (const float*)d_in[13];
    float* out = (float*)d_out;

    dim3 grid(BATCHSZ * NCELLS / 2);   // 2000 single-wave blocks (2 cells each)
    dim3 block(64);
    phinn_sde_kernel<<<grid, block, 0, stream>>>(x, dw, pw1, pb1, pw2, pb2,
                                                 pw3, pb3, pw4, pb4, pw5, pb5,
                                                 tw, tb, out);
}